// Round 4
// baseline (106.646 us; speedup 1.0000x reference)
//
#include <hip/hip_runtime.h>
#include <math.h>

#define N_PTS   2048
#define BLOCK   256
#define NQ      8      // queries per thread -> 2048 queries per block (whole cloud)
#define SLAB    256    // candidates staged per block
#define NSLAB   (N_PTS / SLAB)   // 8 slab-blocks per (dir,bs) group
#define NGRP    64               // 2 dir * 32 bs
#define PBASE   0x7F7F7F7Fu      // uint value of the 0x7F byte-poison

// ws layout (uints): [131072 wsmin][64 cnt][1 gdone][64 gpart] = 524804 bytes,
// all poisoned 0x7F by ONE memset. Counters start at PBASE; "all done"
// thresholds are PBASE+k, so no separate zero-init dispatch is needed.
//
// Grid (32 bs, 2 dir, 8 slab) = 512 blocks x 256 threads.
// Phase A (all blocks): round-0-proven min pass -> uint atomicMin into wsmin.
// Phase B (8th block of each group, elected by per-group atomic counter):
//   reduce the group's 2048 mins (coherent atomic-RMW reads) -> sqrt-sum ->
//   group partial via atomicExch.
// Phase C (64th group-finalizer, elected by gdone counter): sum 64 partials,
//   plain-store out (sole writer -> no out memset dispatch needed).
__global__ __launch_bounds__(BLOCK) void chamfer_fused(
    const float* __restrict__ pred,
    const float* __restrict__ tgt,
    unsigned int* __restrict__ ws,
    float* __restrict__ out)
{
    __shared__ float4 sh[SLAB];
    __shared__ float red[BLOCK / 64];
    __shared__ int flag;

    unsigned int* wsmin = ws;
    unsigned int* cnt   = ws + 131072;        // [64]
    unsigned int* gdone = ws + 131072 + 64;   // [1]
    unsigned int* gpart = ws + 131072 + 65;   // [64] float bits

    const int bs   = blockIdx.x;   // 0..31
    const int dir  = blockIdx.y;   // 0..1
    const int slab = blockIdx.z;   // 0..7
    const int tid  = threadIdx.x;

    const float* Abase = (dir ? tgt : pred) + (size_t)bs * N_PTS * 3;  // queries
    const float* Bbase = (dir ? pred : tgt) + (size_t)bs * N_PTS * 3;  // candidates

    // Stage this slab of candidates with |q|^2 precomputed (1 per thread).
    {
        const int j = slab * SLAB + tid;
        const float x = Bbase[3 * j + 0];
        const float y = Bbase[3 * j + 1];
        const float z = Bbase[3 * j + 2];
        sh[tid] = make_float4(x, y, z, x * x + y * y + z * z);
    }
    __syncthreads();

    // Load 8 query points; pre-scale by -2 so the pair op is pure FMA.
    float nx[NQ], ny[NQ], nz[NQ], p2[NQ], best[NQ];
    #pragma unroll
    for (int k = 0; k < NQ; ++k) {
        const int q = tid + BLOCK * k;
        const float px = Abase[3 * q + 0];
        const float py = Abase[3 * q + 1];
        const float pz = Abase[3 * q + 2];
        nx[k] = -2.0f * px;
        ny[k] = -2.0f * py;
        nz[k] = -2.0f * pz;
        p2[k] = px * px + py * py + pz * pz;
        best[k] = 3.4e38f;
    }

    // Hot loop: 2 candidates/step; fminf(fminf(best,v0),v1) -> v_min3_f32.
    #pragma unroll 2
    for (int j = 0; j < SLAB; j += 2) {
        const float4 t0 = sh[j];
        const float4 t1 = sh[j + 1];
        #pragma unroll
        for (int k = 0; k < NQ; ++k) {
            const float v0 = fmaf(nx[k], t0.x,
                             fmaf(ny[k], t0.y,
                             fmaf(nz[k], t0.z, t0.w)));   // |q|^2 - 2 p.q
            const float v1 = fmaf(nx[k], t1.x,
                             fmaf(ny[k], t1.y,
                             fmaf(nz[k], t1.z, t1.w)));
            best[k] = fminf(fminf(best[k], v0), v1);
        }
    }

    // Combine partial mins across slab-blocks via uint atomicMin (d2 >= 0).
    const int g    = dir * 32 + bs;           // group id 0..63
    const int base = g * N_PTS;
    #pragma unroll
    for (int k = 0; k < NQ; ++k) {
        const float d2 = fmaxf(p2[k] + best[k], 0.0f);
        atomicMin(&wsmin[base + tid + BLOCK * k], __float_as_uint(d2));
    }

    // ---- last-block election for this group (canonical pattern) ----
    __threadfence();          // release this thread's atomicMins device-wide
    __syncthreads();          // all threads of the block fenced
    if (tid == 0)
        flag = (atomicAdd(&cnt[g], 1u) == PBASE + (NSLAB - 1)) ? 1 : 0;
    __syncthreads();

    if (flag) {
        // Phase B: all 8 slab-blocks of group g are done; reduce its 2048 mins.
        // Coherent reads via no-op atomic RMW (umin with 0xFFFFFFFF).
        float s = 0.0f;
        #pragma unroll
        for (int u = 0; u < NQ; ++u) {
            const unsigned int b =
                atomicMin(&wsmin[base + tid + BLOCK * u], 0xFFFFFFFFu);
            s += sqrtf(__uint_as_float(b));   // already clamped >= 0
        }
        for (int off = 32; off > 0; off >>= 1)
            s += __shfl_down(s, off, 64);
        if ((tid & 63) == 0) red[tid >> 6] = s;
        __syncthreads();

        if (tid == 0) {
            const float blk = red[0] + red[1] + red[2] + red[3];
            atomicExch(&gpart[g], __float_as_uint(blk));   // coherent publish
            __threadfence();
            flag = (atomicAdd(gdone, 1u) == PBASE + (NGRP - 1)) ? 2 : 1;
        }
        __syncthreads();

        if (flag == 2 && tid < 64) {
            // Phase C: final 64-partial sum on one wave; sole writer of out.
            float v = __uint_as_float(atomicMin(&gpart[tid], 0xFFFFFFFFu));
            for (int off = 32; off > 0; off >>= 1)
                v += __shfl_down(v, off, 64);
            if (tid == 0)
                out[0] = v * (1.0f / 65536.0f);   // 1/(B*S*N), N==M
        }
    }
}

extern "C" void kernel_launch(void* const* d_in, const int* in_sizes, int n_in,
                              void* d_out, int out_size, void* d_ws, size_t ws_size,
                              hipStream_t stream) {
    const float* pred = (const float*)d_in[0];
    const float* tgt  = (const float*)d_in[1];
    float* out = (float*)d_out;
    unsigned int* ws = (unsigned int*)d_ws;

    // One poison-init covers wsmin + counters + partials (131201 uints).
    hipMemsetAsync(ws, 0x7F, (size_t)131201 * sizeof(unsigned int), stream);

    dim3 grid(32, 2, NSLAB);
    chamfer_fused<<<grid, BLOCK, 0, stream>>>(pred, tgt, ws, out);
}